// Round 16
// baseline (79.264 us; speedup 1.0000x reference)
//
#include <hip/hip_runtime.h>
#include <cstdint>
#include <cstddef>

// Problem constants
#define NB 2
#define NF 8
#define NS 4
#define NK 90      // real K (dirs per shell)
#define NP 642     // grid vertices
#define NXYZ 1728  // 12*12*12
#define MT 64      // p-tile
#define PTILES 11  // ceil(642/64)
#define NG 108     // xyz 16-groups (1728/16)
#define XT_TASKS (64 * NG * 3)          // 20736 x-fragment blocks (1 KB each)
#define WT_TASKS (NS * PTILES * 4 * 3)  // 528 W-fragment blocks
#define GEMM_BLOCKS (64 * PTILES * 3)   // 2112 = 8 * 264 (exact -> bijective)
#define NXCD 8
#define CPX (GEMM_BLOCKS / NXCD)        // 264

typedef __attribute__((ext_vector_type(8))) __bf16 bf16x8;
typedef __attribute__((ext_vector_type(4))) float f32x4;
typedef __attribute__((ext_vector_type(4))) uint32_t u32x4;

// RNE pack of two f32 -> u32 holding 2 bf16 (validated R1-R15)
__device__ __forceinline__ uint32_t pack2bf(float a, float b) {
    uint32_t ua = __builtin_bit_cast(uint32_t, a);
    uint32_t ub = __builtin_bit_cast(uint32_t, b);
    ua += 0x7FFFu + ((ua >> 16) & 1u);
    ub += 0x7FFFu + ((ub >> 16) & 1u);
    return (ua >> 16) | (ub & 0xFFFF0000u);
}

// ============ Kernel 1: pack x and W into MFMA-fragment-order bf16 blocks.
// (R5 structure — fastest prep measured; R13 proved the split is essential.)
__global__ __launch_bounds__(256) void prep_frag(
    const float* __restrict__ x, const float* __restrict__ Wm,
    uint32_t* __restrict__ ws)
{
    const int tid  = (int)threadIdx.x;
    const int lane = tid & 63;
    const int lr = lane & 15, lg = lane >> 4;
    const int task = (int)blockIdx.x * 4 + (tid >> 6);

    float v[8];
    if (task < XT_TASKS) {
        int t = task;
        const int kk = t % 3;   t /= 3;
        const int g  = t % NG;  t /= NG;
        const int e  = t;                  // 0..63
        const int s = e & 3, bf = e >> 2;
        const float* src = x + (size_t)bf * (NS * NK * NXYZ)
                             + (size_t)s * (NK * NXYZ) + g * 16 + lr;
        #pragma unroll
        for (int j = 0; j < 8; ++j) {
            const int k = kk * 32 + lg * 8 + j;
            v[j] = (k < NK) ? src[(size_t)k * NXYZ] : 0.f;
        }
    } else {
        int t = task - XT_TASKS;
        const int kk = t % 3;      t /= 3;
        const int ni = t % 4;      t /= 4;
        const int pt = t % PTILES; t /= PTILES;
        const int s  = t;                  // 0..3
        const int p = pt * MT + ni * 16 + lr;
        const float* src = Wm + (size_t)s * (NK * NP) + p;
        #pragma unroll
        for (int j = 0; j < 8; ++j) {
            const int k = kk * 32 + lg * 8 + j;
            v[j] = (k < NK && p < NP) ? src[(size_t)k * NP] : 0.f;
        }
    }
    u32x4 u;
    u.x = pack2bf(v[0], v[1]);
    u.y = pack2bf(v[2], v[3]);
    u.z = pack2bf(v[4], v[5]);
    u.w = pack2bf(v[6], v[7]);
    *(u32x4*)((char*)ws + (size_t)task * 1024 + lane * 16) = u;
}

// ============ Kernel 2: HEX-n32 GEMM (6 halves per wave). Wave = (e, pt,
// 192-col group): 12 A-frags loaded once, reused across 6 n32-halves;
// B-frags ping-ponged (bA/bB) so half h+1's loads hide under half h's
// MFMA+stores. Per wave: 48 loads, 144 MFMA, 48 stores (R15: 30/72/24).
// Waves 12672 -> 6336; A-frag ws-traffic halves again. ~150 VGPR -> 3/SIMD.
// Block = (e, pt, g3), 3 waves; g3-siblings complete full output rows.
// T1 bijective XCD swizzle (2112 = 8*264).
__global__ __launch_bounds__(192, 3) void gemm_frag6n(
    const uint32_t* __restrict__ ws, float* __restrict__ y)
{
    const int tid  = (int)threadIdx.x;
    const int lane = tid & 63;
    const int lr = lane & 15, lg = lane >> 4;
    const int w    = tid >> 6;                 // 0..2

    const int i = (int)blockIdx.x;
    const int orig = (i % NXCD) * CPX + i / NXCD;   // bijective: 2112 = 8*264
    const int g3 = orig % 3;
    const int pt = (orig / 3) % PTILES;
    const int e  = orig / 33;                       // 0..63
    const int wg = g3 * 3 + w;                      // 0..8, 192 cols each
    const int s = e & 3, bf = e >> 2;

    const char* base  = (const char*)ws + (size_t)lane * 16;
    // B-frag (h, mi, kk): g = wg*12 + h*2 + mi -> offset (h*6 + mi*3 + kk) KB
    const char* xbase = base + (size_t)((e * NG + wg * 12) * 3) * 1024;
    const char* abase = base + (size_t)(XT_TASKS + ((s * PTILES + pt) * 4) * 3) * 1024;

    // A-frags: loaded once, reused for all 6 halves.
    bf16x8 afr[4][3];
    #pragma unroll
    for (int ni = 0; ni < 4; ++ni)
        #pragma unroll
        for (int kk = 0; kk < 3; ++kk)
            afr[ni][kk] = *(const bf16x8*)(abase + (ni * 3 + kk) * 1024);

    const int b = bf >> 3, f = bf & 7;
    const size_t chan = (size_t)b * (NS * NF) + (size_t)s * NF + f;
    float* ybase = y + chan * ((size_t)NP * NXYZ) + wg * 192 + lg * 4;

    bf16x8 bA[6], bB[6];   // ping-pong: 6 frags = one half (2 g x 3 kk)

    // load half 0 into bA
    #pragma unroll
    for (int q = 0; q < 6; ++q)
        bA[q] = *(const bf16x8*)(xbase + q * 1024);

#define COMPUTE_STORE(BSET, H)                                              \
    {                                                                       \
        f32x4 acc[2][4];                                                    \
        _Pragma("unroll")                                                   \
        for (int kk = 0; kk < 3; ++kk)                                      \
            _Pragma("unroll")                                               \
            for (int mi = 0; mi < 2; ++mi)                                  \
                _Pragma("unroll")                                           \
                for (int ni = 0; ni < 4; ++ni)                              \
                    acc[mi][ni] = __builtin_amdgcn_mfma_f32_16x16x32_bf16(  \
                        BSET[mi * 3 + kk], afr[ni][kk],                     \
                        kk ? acc[mi][ni] : (f32x4){0.f, 0.f, 0.f, 0.f},     \
                        0, 0, 0);                                           \
        float* yh = ybase + (H) * 32;                                       \
        _Pragma("unroll")                                                   \
        for (int ni = 0; ni < 4; ++ni) {                                    \
            const int p = pt * MT + ni * 16 + lr;                           \
            if (p < NP) {                                                   \
                float* dst = yh + (size_t)p * NXYZ;                         \
                *(f32x4*)dst = acc[0][ni];                                  \
                *(f32x4*)(dst + 16) = acc[1][ni];                           \
            }                                                               \
        }                                                                   \
    }

#define PREFETCH(BSET, H)                                                   \
    _Pragma("unroll")                                                       \
    for (int q = 0; q < 6; ++q)                                             \
        BSET[q] = *(const bf16x8*)(xbase + ((H) * 6 + q) * 1024);

    PREFETCH(bB, 1)  COMPUTE_STORE(bA, 0)
    PREFETCH(bA, 2)  COMPUTE_STORE(bB, 1)
    PREFETCH(bB, 3)  COMPUTE_STORE(bA, 2)
    PREFETCH(bA, 4)  COMPUTE_STORE(bB, 3)
    PREFETCH(bB, 5)  COMPUTE_STORE(bA, 4)
    COMPUTE_STORE(bB, 5)
#undef COMPUTE_STORE
#undef PREFETCH
}

// ============ Fallback (round-3 structure) if ws too small ================
#define NT 96
#define NTILES 18
#define KP 96
#define ROWB (KP * 2)

__global__ __launch_bounds__(192, 4) void interp_fallback(
    const float* __restrict__ x, const float* __restrict__ Wm,
    float* __restrict__ y)
{
    __shared__ __align__(16) char As[MT * ROWB];
    __shared__ __align__(16) char Bs[NT * ROWB];

    int blk = (int)blockIdx.x;
    const int nt = blk % NTILES; blk /= NTILES;
    const int f  = blk % NF;     blk /= NF;
    const int s  = blk % NS;     blk /= NS;
    const int b  = blk;
    const int tid = (int)threadIdx.x;
    const int n0 = nt * NT;

    {
        const int c  = tid % NT;
        const int kh = tid / NT;
        const float* xp = x + (((size_t)b * NF + f) * (NS * NK) + (size_t)s * NK) * NXYZ
                            + n0 + c;
        const int cs = (c & 7) << 4;
        #pragma unroll
        for (int kk = 0; kk < 48; kk += 8) {
            const int kb = kh * 48 + kk;
            float v[8];
            #pragma unroll
            for (int j = 0; j < 8; ++j) {
                const int k = kb + j;
                v[j] = (k < NK) ? xp[(size_t)k * NXYZ] : 0.f;
            }
            u32x4 u;
            u.x = pack2bf(v[0], v[1]); u.y = pack2bf(v[2], v[3]);
            u.z = pack2bf(v[4], v[5]); u.w = pack2bf(v[6], v[7]);
            *(u32x4*)(Bs + ((c * ROWB + kb * 2) ^ cs)) = u;
        }
    }

    const int lane = tid & 63;
    const int w  = tid / 64;
    const int lr = lane & 15;
    const int lg = lane >> 4;
    const int ls = (lr & 7) << 4;
    const size_t chan = (size_t)b * (NS * NF) + (size_t)s * NF + f;
    float* ybase = y + chan * ((size_t)NP * NXYZ);
    const int xyzbase = n0 + w * 32 + lg * 4;
    const int ar = tid & 63;
    const int akc = tid >> 6;
    const int ars = (ar & 7) << 4;

    for (int pt = 0; pt < PTILES; ++pt) {
        const int p0 = pt * MT;
        __syncthreads();
        {
            const int p = p0 + ar;
            const bool pv = (p < NP);
            const float* wp = Wm + (size_t)s * NK * NP + p;
            #pragma unroll
            for (int kk = 0; kk < 32; kk += 8) {
                const int kb = akc * 32 + kk;
                float v[8];
                #pragma unroll
                for (int j = 0; j < 8; ++j) {
                    const int k = kb + j;
                    v[j] = (pv && (k < NK)) ? wp[(size_t)k * NP] : 0.f;
                }
                u32x4 u;
                u.x = pack2bf(v[0], v[1]); u.y = pack2bf(v[2], v[3]);
                u.z = pack2bf(v[4], v[5]); u.w = pack2bf(v[6], v[7]);
                *(u32x4*)(As + ((ar * ROWB + kb * 2) ^ ars)) = u;
            }
        }
        __syncthreads();

        f32x4 acc[2][4];
        #pragma unroll
        for (int mi = 0; mi < 2; ++mi)
            #pragma unroll
            for (int ni = 0; ni < 4; ++ni)
                acc[mi][ni] = (f32x4){0.f, 0.f, 0.f, 0.f};

        #pragma unroll
        for (int kk = 0; kk < 3; ++kk) {
            const int kbyte = kk * 64 + lg * 16;
            bf16x8 bxyz[2], ap[4];
            #pragma unroll
            for (int mi = 0; mi < 2; ++mi) {
                const int row = w * 32 + mi * 16 + lr;
                bxyz[mi] = *(const bf16x8*)(Bs + ((row * ROWB + kbyte) ^ ls));
            }
            #pragma unroll
            for (int ni = 0; ni < 4; ++ni) {
                const int row = ni * 16 + lr;
                ap[ni] = *(const bf16x8*)(As + ((row * ROWB + kbyte) ^ ls));
            }
            #pragma unroll
            for (int mi = 0; mi < 2; ++mi)
                #pragma unroll
                for (int ni = 0; ni < 4; ++ni)
                    acc[mi][ni] = __builtin_amdgcn_mfma_f32_16x16x32_bf16(
                        bxyz[mi], ap[ni], acc[mi][ni], 0, 0, 0);
        }

        #pragma unroll
        for (int ni = 0; ni < 4; ++ni) {
            const int p = p0 + ni * 16 + lr;
            if (p < NP) {
                float* dst = ybase + (size_t)p * NXYZ + xyzbase;
                *(f32x4*)dst = acc[0][ni];
                *(f32x4*)(dst + 16) = acc[1][ni];
            }
        }
    }
}

extern "C" void kernel_launch(void* const* d_in, const int* in_sizes, int n_in,
                              void* d_out, int out_size, void* d_ws, size_t ws_size,
                              hipStream_t stream) {
    (void)in_sizes; (void)n_in; (void)out_size;
    const float* x  = (const float*)d_in[0];
    const float* Wm = (const float*)d_in[1];
    float* y = (float*)d_out;

    const size_t ws_need = (size_t)(XT_TASKS + WT_TASKS) * 1024;  // ~21.8 MB
    if (ws_size >= ws_need) {
        prep_frag<<<(XT_TASKS + WT_TASKS) / 4, 256, 0, stream>>>(x, Wm, (uint32_t*)d_ws);
        gemm_frag6n<<<GEMM_BLOCKS, 192, 0, stream>>>((const uint32_t*)d_ws, y);
    } else {
        interp_fallback<<<NB * NS * NF * NTILES, 192, 0, stream>>>(x, Wm, y);
    }
}

// Round 17
// 74.205 us; speedup vs baseline: 1.0682x; 1.0682x over previous
//
#include <hip/hip_runtime.h>
#include <cstdint>
#include <cstddef>

// Problem constants
#define NB 2
#define NF 8
#define NS 4
#define NK 90      // real K (dirs per shell)
#define NP 642     // grid vertices
#define NXYZ 1728  // 12*12*12
#define MT 64      // p-tile
#define PTILES 11  // ceil(642/64)
#define NG 108     // xyz 16-groups (1728/16)
#define XT_TASKS (64 * NG * 3)          // 20736 x-fragment blocks (1 KB each)
#define WT_TASKS (NS * PTILES * 4 * 3)  // 528 W-fragment blocks
#define NWG 18                          // wave-groups of 96 cols (1728/96)
#define GEMM_BLOCKS (64 * PTILES * 6)   // 4224 = 8 * 528 (exact -> bijective)
#define NXCD 8
#define CPX (GEMM_BLOCKS / NXCD)        // 528

typedef __attribute__((ext_vector_type(8))) __bf16 bf16x8;
typedef __attribute__((ext_vector_type(4))) float f32x4;
typedef __attribute__((ext_vector_type(4))) uint32_t u32x4;

// RNE pack of two f32 -> u32 holding 2 bf16 (validated R1-R16)
__device__ __forceinline__ uint32_t pack2bf(float a, float b) {
    uint32_t ua = __builtin_bit_cast(uint32_t, a);
    uint32_t ub = __builtin_bit_cast(uint32_t, b);
    ua += 0x7FFFu + ((ua >> 16) & 1u);
    ub += 0x7FFFu + ((ub >> 16) & 1u);
    return (ua >> 16) | (ub & 0xFFFF0000u);
}

// ============ Kernel 1: pack x and W into MFMA-fragment-order bf16 blocks.
// (R5 structure — fastest prep measured; R13 proved the split is essential.)
__global__ __launch_bounds__(256) void prep_frag(
    const float* __restrict__ x, const float* __restrict__ Wm,
    uint32_t* __restrict__ ws)
{
    const int tid  = (int)threadIdx.x;
    const int lane = tid & 63;
    const int lr = lane & 15, lg = lane >> 4;
    const int task = (int)blockIdx.x * 4 + (tid >> 6);

    float v[8];
    if (task < XT_TASKS) {
        int t = task;
        const int kk = t % 3;   t /= 3;
        const int g  = t % NG;  t /= NG;
        const int e  = t;                  // 0..63
        const int s = e & 3, bf = e >> 2;
        const float* src = x + (size_t)bf * (NS * NK * NXYZ)
                             + (size_t)s * (NK * NXYZ) + g * 16 + lr;
        #pragma unroll
        for (int j = 0; j < 8; ++j) {
            const int k = kk * 32 + lg * 8 + j;
            v[j] = (k < NK) ? src[(size_t)k * NXYZ] : 0.f;
        }
    } else {
        int t = task - XT_TASKS;
        const int kk = t % 3;      t /= 3;
        const int ni = t % 4;      t /= 4;
        const int pt = t % PTILES; t /= PTILES;
        const int s  = t;                  // 0..3
        const int p = pt * MT + ni * 16 + lr;
        const float* src = Wm + (size_t)s * (NK * NP) + p;
        #pragma unroll
        for (int j = 0; j < 8; ++j) {
            const int k = kk * 32 + lg * 8 + j;
            v[j] = (k < NK && p < NP) ? src[(size_t)k * NP] : 0.f;
        }
    }
    u32x4 u;
    u.x = pack2bf(v[0], v[1]);
    u.y = pack2bf(v[2], v[3]);
    u.z = pack2bf(v[4], v[5]);
    u.w = pack2bf(v[6], v[7]);
    *(u32x4*)((char*)ws + (size_t)task * 1024 + lane * 16) = u;
}

// ============ Kernel 2: TRIPLE-n32 GEMM (R15 optimum — session best 73.7 µs).
// Wave = (e, pt, wave-group of 96 cols): 12 A-frags loaded once, reused
// across 3 n32-halves; B-frags ping-ponged (bA/bB) so half h+1's loads hide
// under half h's MFMA+stores. Per wave: 30 loads, 72 MFMA, 24 stores.
// Amortization curve measured: 2x=-4.6us, 3x=-1.7us, 6x=+5.6us -> 3x optimal.
// Block = (e, pt, sext), 3 waves; sext fastest -> 6 sibling blocks complete
// full 6.9 KB output rows. T1 bijective XCD swizzle (4224 = 8*528).
__global__ __launch_bounds__(192, 3) void gemm_frag3n(
    const uint32_t* __restrict__ ws, float* __restrict__ y)
{
    const int tid  = (int)threadIdx.x;
    const int lane = tid & 63;
    const int lr = lane & 15, lg = lane >> 4;
    const int w    = tid >> 6;                 // 0..2

    const int i = (int)blockIdx.x;
    const int orig = (i % NXCD) * CPX + i / NXCD;   // bijective: 4224 = 8*528
    const int sext = orig % 6;
    const int pt   = (orig / 6) % PTILES;
    const int e    = orig / 66;                     // 0..63
    const int wg   = sext * 3 + w;                  // 0..17, 96 cols each
    const int s = e & 3, bf = e >> 2;

    const char* base  = (const char*)ws + (size_t)lane * 16;
    // B-frag (h, mi, kk): g = wg*6 + h*2 + mi
    const char* xbase = base + (size_t)((e * NG + wg * 6) * 3) * 1024;
    const char* abase = base + (size_t)(XT_TASKS + ((s * PTILES + pt) * 4) * 3) * 1024;

    // A-frags: loaded once, reused for all 3 halves.
    bf16x8 afr[4][3];
    #pragma unroll
    for (int ni = 0; ni < 4; ++ni)
        #pragma unroll
        for (int kk = 0; kk < 3; ++kk)
            afr[ni][kk] = *(const bf16x8*)(abase + (ni * 3 + kk) * 1024);

    const int b = bf >> 3, f = bf & 7;
    const size_t chan = (size_t)b * (NS * NF) + (size_t)s * NF + f;
    float* ybase = y + chan * ((size_t)NP * NXYZ) + wg * 96 + lg * 4;

    bf16x8 bA[6], bB[6];   // ping-pong: 6 frags = one half (2 g x 3 kk)

    // load half 0 into bA
    #pragma unroll
    for (int q = 0; q < 6; ++q)
        bA[q] = *(const bf16x8*)(xbase + q * 1024);

#define COMPUTE_STORE(BSET, H)                                              \
    {                                                                       \
        f32x4 acc[2][4];                                                    \
        _Pragma("unroll")                                                   \
        for (int kk = 0; kk < 3; ++kk)                                      \
            _Pragma("unroll")                                               \
            for (int mi = 0; mi < 2; ++mi)                                  \
                _Pragma("unroll")                                           \
                for (int ni = 0; ni < 4; ++ni)                              \
                    acc[mi][ni] = __builtin_amdgcn_mfma_f32_16x16x32_bf16(  \
                        BSET[mi * 3 + kk], afr[ni][kk],                     \
                        kk ? acc[mi][ni] : (f32x4){0.f, 0.f, 0.f, 0.f},     \
                        0, 0, 0);                                           \
        float* yh = ybase + (H) * 32;                                       \
        _Pragma("unroll")                                                   \
        for (int ni = 0; ni < 4; ++ni) {                                    \
            const int p = pt * MT + ni * 16 + lr;                           \
            if (p < NP) {                                                   \
                float* dst = yh + (size_t)p * NXYZ;                         \
                *(f32x4*)dst = acc[0][ni];                                  \
                *(f32x4*)(dst + 16) = acc[1][ni];                           \
            }                                                               \
        }                                                                   \
    }

    // h=0: prefetch half 1 into bB, compute/store from bA
    #pragma unroll
    for (int q = 0; q < 6; ++q)
        bB[q] = *(const bf16x8*)(xbase + (6 + q) * 1024);
    COMPUTE_STORE(bA, 0)

    // h=1: prefetch half 2 into bA, compute/store from bB
    #pragma unroll
    for (int q = 0; q < 6; ++q)
        bA[q] = *(const bf16x8*)(xbase + (12 + q) * 1024);
    COMPUTE_STORE(bB, 1)

    // h=2: compute/store from bA
    COMPUTE_STORE(bA, 2)
#undef COMPUTE_STORE
}

// ============ Fallback (round-3 structure) if ws too small ================
#define NT 96
#define NTILES 18
#define KP 96
#define ROWB (KP * 2)

__global__ __launch_bounds__(192, 4) void interp_fallback(
    const float* __restrict__ x, const float* __restrict__ Wm,
    float* __restrict__ y)
{
    __shared__ __align__(16) char As[MT * ROWB];
    __shared__ __align__(16) char Bs[NT * ROWB];

    int blk = (int)blockIdx.x;
    const int nt = blk % NTILES; blk /= NTILES;
    const int f  = blk % NF;     blk /= NF;
    const int s  = blk % NS;     blk /= NS;
    const int b  = blk;
    const int tid = (int)threadIdx.x;
    const int n0 = nt * NT;

    {
        const int c  = tid % NT;
        const int kh = tid / NT;
        const float* xp = x + (((size_t)b * NF + f) * (NS * NK) + (size_t)s * NK) * NXYZ
                            + n0 + c;
        const int cs = (c & 7) << 4;
        #pragma unroll
        for (int kk = 0; kk < 48; kk += 8) {
            const int kb = kh * 48 + kk;
            float v[8];
            #pragma unroll
            for (int j = 0; j < 8; ++j) {
                const int k = kb + j;
                v[j] = (k < NK) ? xp[(size_t)k * NXYZ] : 0.f;
            }
            u32x4 u;
            u.x = pack2bf(v[0], v[1]); u.y = pack2bf(v[2], v[3]);
            u.z = pack2bf(v[4], v[5]); u.w = pack2bf(v[6], v[7]);
            *(u32x4*)(Bs + ((c * ROWB + kb * 2) ^ cs)) = u;
        }
    }

    const int lane = tid & 63;
    const int w  = tid / 64;
    const int lr = lane & 15;
    const int lg = lane >> 4;
    const int ls = (lr & 7) << 4;
    const size_t chan = (size_t)b * (NS * NF) + (size_t)s * NF + f;
    float* ybase = y + chan * ((size_t)NP * NXYZ);
    const int xyzbase = n0 + w * 32 + lg * 4;
    const int ar = tid & 63;
    const int akc = tid >> 6;
    const int ars = (ar & 7) << 4;

    for (int pt = 0; pt < PTILES; ++pt) {
        const int p0 = pt * MT;
        __syncthreads();
        {
            const int p = p0 + ar;
            const bool pv = (p < NP);
            const float* wp = Wm + (size_t)s * NK * NP + p;
            #pragma unroll
            for (int kk = 0; kk < 32; kk += 8) {
                const int kb = akc * 32 + kk;
                float v[8];
                #pragma unroll
                for (int j = 0; j < 8; ++j) {
                    const int k = kb + j;
                    v[j] = (pv && (k < NK)) ? wp[(size_t)k * NP] : 0.f;
                }
                u32x4 u;
                u.x = pack2bf(v[0], v[1]); u.y = pack2bf(v[2], v[3]);
                u.z = pack2bf(v[4], v[5]); u.w = pack2bf(v[6], v[7]);
                *(u32x4*)(As + ((ar * ROWB + kb * 2) ^ ars)) = u;
            }
        }
        __syncthreads();

        f32x4 acc[2][4];
        #pragma unroll
        for (int mi = 0; mi < 2; ++mi)
            #pragma unroll
            for (int ni = 0; ni < 4; ++ni)
                acc[mi][ni] = (f32x4){0.f, 0.f, 0.f, 0.f};

        #pragma unroll
        for (int kk = 0; kk < 3; ++kk) {
            const int kbyte = kk * 64 + lg * 16;
            bf16x8 bxyz[2], ap[4];
            #pragma unroll
            for (int mi = 0; mi < 2; ++mi) {
                const int row = w * 32 + mi * 16 + lr;
                bxyz[mi] = *(const bf16x8*)(Bs + ((row * ROWB + kbyte) ^ ls));
            }
            #pragma unroll
            for (int ni = 0; ni < 4; ++ni) {
                const int row = ni * 16 + lr;
                ap[ni] = *(const bf16x8*)(As + ((row * ROWB + kbyte) ^ ls));
            }
            #pragma unroll
            for (int mi = 0; mi < 2; ++mi)
                #pragma unroll
                for (int ni = 0; ni < 4; ++ni)
                    acc[mi][ni] = __builtin_amdgcn_mfma_f32_16x16x32_bf16(
                        bxyz[mi], ap[ni], acc[mi][ni], 0, 0, 0);
        }

        #pragma unroll
        for (int ni = 0; ni < 4; ++ni) {
            const int p = p0 + ni * 16 + lr;
            if (p < NP) {
                float* dst = ybase + (size_t)p * NXYZ + xyzbase;
                *(f32x4*)dst = acc[0][ni];
                *(f32x4*)(dst + 16) = acc[1][ni];
            }
        }
    }
}

extern "C" void kernel_launch(void* const* d_in, const int* in_sizes, int n_in,
                              void* d_out, int out_size, void* d_ws, size_t ws_size,
                              hipStream_t stream) {
    (void)in_sizes; (void)n_in; (void)out_size;
    const float* x  = (const float*)d_in[0];
    const float* Wm = (const float*)d_in[1];
    float* y = (float*)d_out;

    const size_t ws_need = (size_t)(XT_TASKS + WT_TASKS) * 1024;  // ~21.8 MB
    if (ws_size >= ws_need) {
        prep_frag<<<(XT_TASKS + WT_TASKS) / 4, 256, 0, stream>>>(x, Wm, (uint32_t*)d_ws);
        gemm_frag3n<<<GEMM_BLOCKS, 192, 0, stream>>>((const uint32_t*)d_ws, y);
    } else {
        interp_fallback<<<NB * NS * NF * NTILES, 192, 0, stream>>>(x, Wm, y);
    }
}